// Round 9
// baseline (165.470 us; speedup 1.0000x reference)
//
#include <hip/hip_runtime.h>

typedef float f32x4 __attribute__((ext_vector_type(4)));

#define N_TOKENS 131072
#define D_MODEL  512
#define PATHS    16
#define CAP      16384            // CAP_FACTOR * N / P
#define TPB      256
#define NBLK     (N_TOKENS / TPB) // 512 token blocks (argmax/scan granularity)
#define F4_ROW   (D_MODEL / 4)    // 128 f32x4 per row
#define ROWS_TOTAL (PATHS * CAP)  // 262144

#define TOK_PER_SWG 128                          // tokens per scatter wg
#define SC_WGS   (N_TOKENS / TOK_PER_SWG)        // 1024
#define R_PER_ZWG 128                            // rows per zero wg
#define ZWGS     (ROWS_TOTAL / R_PER_ZWG)        // 2048

// ---------------------------------------------------------------------------
// Kernel 1: per-token argmax (first-max wins) + stable rank within block +
// per-block per-path histogram.
// ---------------------------------------------------------------------------
__global__ void k_argmax_hist(const float* __restrict__ score,
                              int* __restrict__ packed,
                              int* __restrict__ blkcnt) {
    __shared__ int wcount[TPB / 64][PATHS];
    const int t    = blockIdx.x * TPB + threadIdx.x;
    const int lane = threadIdx.x & 63;
    const int wid  = threadIdx.x >> 6;

    const f32x4* s4 = reinterpret_cast<const f32x4*>(score) + (size_t)t * 4;
    f32x4 a = s4[0], b = s4[1], c = s4[2], d = s4[3];
    float v[16] = {a.x, a.y, a.z, a.w, b.x, b.y, b.z, b.w,
                   c.x, c.y, c.z, c.w, d.x, d.y, d.z, d.w};
    int   myp  = 0;
    float best = v[0];
#pragma unroll
    for (int p = 1; p < 16; ++p) {
        if (v[p] > best) { best = v[p]; myp = p; }   // strict > == first occurrence
    }

    unsigned long long mymask = 0ULL;
#pragma unroll
    for (int p = 0; p < PATHS; ++p) {
        unsigned long long m = __ballot(myp == p);
        if (p == myp) mymask = m;
        if (lane == p) wcount[wid][p] = __popcll(m);
    }
    const int rank_w = __popcll(mymask & ((1ULL << lane) - 1ULL));
    __syncthreads();

    int prefix = 0;
    for (int w = 0; w < wid; ++w) prefix += wcount[w][myp];
    packed[t] = (myp << 16) | (prefix + rank_w);

    if (threadIdx.x < PATHS) {
        int s = 0;
#pragma unroll
        for (int w = 0; w < TPB / 64; ++w) s += wcount[w][threadIdx.x];
        blkcnt[blockIdx.x * PATHS + threadIdx.x] = s;
    }
}

// ---------------------------------------------------------------------------
// Kernel 2: parallel two-level exclusive scan of blkcnt (per path).
// ---------------------------------------------------------------------------
__global__ void k_scan(int* __restrict__ blkcnt, int* __restrict__ cnt) {
    __shared__ int part[16][PATHS + 1];
    const int p = threadIdx.x & 15;
    const int c = threadIdx.x >> 4;
    const int base = c * 32;

    int local[32];
#pragma unroll
    for (int b = 0; b < 32; ++b) local[b] = blkcnt[(base + b) * PATHS + p];
    int s = 0;
#pragma unroll
    for (int b = 0; b < 32; ++b) { int v = local[b]; local[b] = s; s += v; }
    part[c][p] = s;
    __syncthreads();

    if (threadIdx.x < PATHS) {
        int run = 0;
#pragma unroll
        for (int ch = 0; ch < 16; ++ch) {
            int v = part[ch][threadIdx.x];
            part[ch][threadIdx.x] = run;
            run += v;
        }
        cnt[threadIdx.x] = run;
    }
    __syncthreads();

    const int off = part[c][p];
#pragma unroll
    for (int b = 0; b < 32; ++b) blkcnt[(base + b) * PATHS + p] = local[b] + off;
}

// ---------------------------------------------------------------------------
// Kernel 3: PURE-WRITE phase. Zero all empty rows (j >= cnt[p]); contiguous
// 128-row tiles, nontemporal. (Unchanged from R8 — it worked.)
// ---------------------------------------------------------------------------
__global__ void k_zero(const int* __restrict__ cnt, f32x4* __restrict__ out) {
    const int row0 = blockIdx.x * R_PER_ZWG;
    const int p    = row0 >> 14;               // 128 | 16384 -> path constant
    int cp = cnt[p];
    cp = cp > CAP ? CAP : cp;
    const int jrel = row0 & (CAP - 1);
    int nskip = cp - jrel;                     // filled prefix inside this tile
    nskip = nskip < 0 ? 0 : (nskip > R_PER_ZWG ? R_PER_ZWG : nskip);
    if (nskip == R_PER_ZWG) return;            // fully-filled tile

    const int col = threadIdx.x & (F4_ROW - 1);
    const int sub = threadIdx.x >> 7;          // 0..1
    const f32x4 z = {0.f, 0.f, 0.f, 0.f};
#pragma unroll 8
    for (int r = nskip + ((sub - nskip) & 1); r < R_PER_ZWG; r += 2) {
        __builtin_nontemporal_store(z, &out[(size_t)(row0 + r) * F4_ROW + col]);
    }
}

// ---------------------------------------------------------------------------
// Kernel 4: PURE-COPY phase, token-ordered scatter. Reads are fully
// SEQUENTIAL (256 KB window per wg); writes land in 16 ascending per-path
// streams of ~16 KB contiguous chunks (consecutive same-path tokens ->
// consecutive slots). Destinations LDS-hoisted; unroll 8; all nt.
// ---------------------------------------------------------------------------
__global__ void k_scatter(const f32x4* __restrict__ inputs,
                          const int* __restrict__ packed,
                          const int* __restrict__ blkoff,
                          f32x4* __restrict__ out) {
    __shared__ int dst[TOK_PER_SWG];
    const int blk = blockIdx.x;                   // 0..1023
    if (threadIdx.x < TOK_PER_SWG) {
        const int t  = blk * TOK_PER_SWG + threadIdx.x;
        const int pk = packed[t];
        const int p  = pk >> 16;
        const int r  = pk & 0xffff;
        const int pos = blkoff[(t >> 8) * PATHS + p] + r;  // rank per 256-block
        dst[threadIdx.x] = (pos < CAP) ? p * CAP + pos : -1;
    }
    __syncthreads();

    const int col = threadIdx.x & (F4_ROW - 1);   // 0..127
    const int sub = threadIdx.x >> 7;             // 0..1 (2 rows per pass)
    const size_t in0 = (size_t)blk * TOK_PER_SWG * F4_ROW;
#pragma unroll 8
    for (int r = sub; r < TOK_PER_SWG; r += 2) {
        const f32x4 v = __builtin_nontemporal_load(
            &inputs[in0 + (size_t)r * F4_ROW + col]);
        const int d = dst[r];
        if (d >= 0)
            __builtin_nontemporal_store(v, &out[(size_t)d * F4_ROW + col]);
    }
}

// ---------------------------------------------------------------------------
extern "C" void kernel_launch(void* const* d_in, const int* in_sizes, int n_in,
                              void* d_out, int out_size, void* d_ws, size_t ws_size,
                              hipStream_t stream) {
    const float* inputs = (const float*)d_in[0];
    const float* score  = (const float*)d_in[1];
    float*       out    = (float*)d_out;

    // Workspace (ints): packed[N] | blkcnt[NBLK*P] | cnt[P]
    int* w      = (int*)d_ws;
    int* packed = w;
    int* blkcnt = packed + N_TOKENS;
    int* cnt    = blkcnt + NBLK * PATHS;

    k_argmax_hist<<<NBLK, TPB, 0, stream>>>(score, packed, blkcnt);
    k_scan<<<1, TPB, 0, stream>>>(blkcnt, cnt);
    // Phase-pure big streams: pure write first, then 1:1 token-ordered scatter.
    k_zero<<<ZWGS, TPB, 0, stream>>>(cnt, (f32x4*)out);
    k_scatter<<<SC_WGS, TPB, 0, stream>>>(
        (const f32x4*)inputs, packed, blkcnt, (f32x4*)out);
}

// Round 10
// 161.150 us; speedup vs baseline: 1.0268x; 1.0268x over previous
//
#include <hip/hip_runtime.h>

typedef float f32x4 __attribute__((ext_vector_type(4)));

#define N_TOKENS 131072
#define D_MODEL  512
#define PATHS    16
#define CAP      16384            // CAP_FACTOR * N / P
#define TPB      256
#define NBLK     (N_TOKENS / TPB) // 512 token blocks
#define F4_ROW   (D_MODEL / 4)    // 128 f32x4 per row
#define ROWS_TOTAL (PATHS * CAP)  // 262144

#define R_PER_CWG 64                             // rows per copy wg
#define COPY_WGS  (ROWS_TOTAL / R_PER_CWG)       // 4096
#define R_PER_ZWG 128                            // rows per zero wg
#define ZWGS      (ROWS_TOTAL / R_PER_ZWG)       // 2048
#define BATCH     8                              // rows buffered per burst

// ---------------------------------------------------------------------------
// Kernel 1: per-token argmax (first-max wins) + stable rank within block +
// per-block per-path histogram.
// ---------------------------------------------------------------------------
__global__ void k_argmax_hist(const float* __restrict__ score,
                              int* __restrict__ packed,
                              int* __restrict__ blkcnt) {
    __shared__ int wcount[TPB / 64][PATHS];
    const int t    = blockIdx.x * TPB + threadIdx.x;
    const int lane = threadIdx.x & 63;
    const int wid  = threadIdx.x >> 6;

    const f32x4* s4 = reinterpret_cast<const f32x4*>(score) + (size_t)t * 4;
    f32x4 a = s4[0], b = s4[1], c = s4[2], d = s4[3];
    float v[16] = {a.x, a.y, a.z, a.w, b.x, b.y, b.z, b.w,
                   c.x, c.y, c.z, c.w, d.x, d.y, d.z, d.w};
    int   myp  = 0;
    float best = v[0];
#pragma unroll
    for (int p = 1; p < 16; ++p) {
        if (v[p] > best) { best = v[p]; myp = p; }   // strict > == first occurrence
    }

    unsigned long long mymask = 0ULL;
#pragma unroll
    for (int p = 0; p < PATHS; ++p) {
        unsigned long long m = __ballot(myp == p);
        if (p == myp) mymask = m;
        if (lane == p) wcount[wid][p] = __popcll(m);
    }
    const int rank_w = __popcll(mymask & ((1ULL << lane) - 1ULL));
    __syncthreads();

    int prefix = 0;
    for (int w = 0; w < wid; ++w) prefix += wcount[w][myp];
    packed[t] = (myp << 16) | (prefix + rank_w);

    if (threadIdx.x < PATHS) {
        int s = 0;
#pragma unroll
        for (int w = 0; w < TPB / 64; ++w) s += wcount[w][threadIdx.x];
        blkcnt[blockIdx.x * PATHS + threadIdx.x] = s;
    }
}

// ---------------------------------------------------------------------------
// Kernel 2: parallel two-level exclusive scan of blkcnt (per path).
// ---------------------------------------------------------------------------
__global__ void k_scan(int* __restrict__ blkcnt, int* __restrict__ cnt) {
    __shared__ int part[16][PATHS + 1];
    const int p = threadIdx.x & 15;
    const int c = threadIdx.x >> 4;
    const int base = c * 32;

    int local[32];
#pragma unroll
    for (int b = 0; b < 32; ++b) local[b] = blkcnt[(base + b) * PATHS + p];
    int s = 0;
#pragma unroll
    for (int b = 0; b < 32; ++b) { int v = local[b]; local[b] = s; s += v; }
    part[c][p] = s;
    __syncthreads();

    if (threadIdx.x < PATHS) {
        int run = 0;
#pragma unroll
        for (int ch = 0; ch < 16; ++ch) {
            int v = part[ch][threadIdx.x];
            part[ch][threadIdx.x] = run;
            run += v;
        }
        cnt[threadIdx.x] = run;
    }
    __syncthreads();

    const int off = part[c][p];
#pragma unroll
    for (int b = 0; b < 32; ++b) blkcnt[(base + b) * PATHS + p] = local[b] + off;
}

// ---------------------------------------------------------------------------
// Kernel 3: slot_token[p*CAP + pos] = token id (inverse permutation).
// ---------------------------------------------------------------------------
__global__ void k_slots(const int* __restrict__ packed,
                        const int* __restrict__ blkoff,
                        int* __restrict__ slot_token) {
    const int t  = blockIdx.x * TPB + threadIdx.x;
    const int pk = packed[t];
    const int p  = pk >> 16;
    const int r  = pk & 0xffff;
    const int pos = blkoff[blockIdx.x * PATHS + p] + r;
    if (pos < CAP) slot_token[p * CAP + pos] = t;
}

// ---------------------------------------------------------------------------
// Kernel 4a: PURE-WRITE phase. Zero all empty rows (j >= cnt[p]).
// ---------------------------------------------------------------------------
__global__ void k_zero(const int* __restrict__ cnt, f32x4* __restrict__ out) {
    const int row0 = blockIdx.x * R_PER_ZWG;
    const int p    = row0 >> 14;               // 128 | 16384 -> path constant
    int cp = cnt[p];
    cp = cp > CAP ? CAP : cp;
    const int jrel = row0 & (CAP - 1);
    int nskip = cp - jrel;                     // filled prefix inside this tile
    nskip = nskip < 0 ? 0 : (nskip > R_PER_ZWG ? R_PER_ZWG : nskip);
    if (nskip == R_PER_ZWG) return;            // fully-filled tile

    const int col = threadIdx.x & (F4_ROW - 1);
    const int sub = threadIdx.x >> 7;          // 0..1
    const f32x4 z = {0.f, 0.f, 0.f, 0.f};
#pragma unroll 8
    for (int r = nskip + ((sub - nskip) & 1); r < R_PER_ZWG; r += 2) {
        __builtin_nontemporal_store(z, &out[(size_t)(row0 + r) * F4_ROW + col]);
    }
}

// ---------------------------------------------------------------------------
// Kernel 4b: PURE-COPY phase, dest-ordered, WAVE-LEVEL BURST BATCHED:
// load 8 rows into registers (16 KB read burst per wave), then store 8 rows
// (16 KB write burst). Coarse read/write epochs instead of per-iter interleave.
// ---------------------------------------------------------------------------
__global__ void k_copy(const f32x4* __restrict__ inputs,
                       const int* __restrict__ slot_token,
                       const int* __restrict__ cnt,
                       f32x4* __restrict__ out) {
    __shared__ int toks[R_PER_CWG];
    const int row0 = blockIdx.x * R_PER_CWG;
    const int p    = row0 >> 14;               // CAP = 2^14
    int cp = cnt[p];
    cp = cp > CAP ? CAP : cp;
    const int jrel = row0 & (CAP - 1);
    int ndata = cp - jrel;
    ndata = ndata < 0 ? 0 : (ndata > R_PER_CWG ? R_PER_CWG : ndata);
    if (ndata == 0) return;                    // pure-zero tile

    if (threadIdx.x < ndata)
        toks[threadIdx.x] = slot_token[row0 + threadIdx.x];
    __syncthreads();

    const int col = threadIdx.x & (F4_ROW - 1);
    const int sub = threadIdx.x >> 7;          // 0..1 (2 rows per pass)

    if (ndata == R_PER_CWG) {
        // Full tile: 32 passes per sub-half, 4 batches of 8.
#pragma unroll
        for (int b = 0; b < 4; ++b) {
            f32x4 v[BATCH];
            int   rows[BATCH];
#pragma unroll
            for (int i = 0; i < BATCH; ++i) {
                rows[i] = sub + 2 * (b * BATCH + i);
                v[i] = __builtin_nontemporal_load(
                    &inputs[(size_t)toks[rows[i]] * F4_ROW + col]);
            }
#pragma unroll
            for (int i = 0; i < BATCH; ++i) {
                __builtin_nontemporal_store(
                    v[i], &out[(size_t)(row0 + rows[i]) * F4_ROW + col]);
            }
        }
    } else {
        // Boundary tile (1 per path): simple pipelined loop.
#pragma unroll 8
        for (int r = sub; r < ndata; r += 2) {
            const f32x4 v = __builtin_nontemporal_load(
                &inputs[(size_t)toks[r] * F4_ROW + col]);
            __builtin_nontemporal_store(v, &out[(size_t)(row0 + r) * F4_ROW + col]);
        }
    }
}

// ---------------------------------------------------------------------------
extern "C" void kernel_launch(void* const* d_in, const int* in_sizes, int n_in,
                              void* d_out, int out_size, void* d_ws, size_t ws_size,
                              hipStream_t stream) {
    const float* inputs = (const float*)d_in[0];
    const float* score  = (const float*)d_in[1];
    float*       out    = (float*)d_out;

    // Workspace (ints): packed[N] | blkcnt[NBLK*P] | cnt[P] | slot_token[P*CAP]
    int* w          = (int*)d_ws;
    int* packed     = w;
    int* blkcnt     = packed + N_TOKENS;
    int* cnt        = blkcnt + NBLK * PATHS;
    int* slot_token = cnt + PATHS;

    k_argmax_hist<<<NBLK, TPB, 0, stream>>>(score, packed, blkcnt);
    k_scan<<<1, TPB, 0, stream>>>(blkcnt, cnt);
    k_slots<<<NBLK, TPB, 0, stream>>>(packed, blkcnt, slot_token);
    // Phase-pure big streams: pure write, then burst-batched permuted copy.
    k_zero<<<ZWGS, TPB, 0, stream>>>(cnt, (f32x4*)out);
    k_copy<<<COPY_WGS, TPB, 0, stream>>>(
        (const f32x4*)inputs, slot_token, cnt, (f32x4*)out);
}